// Round 8
// baseline (252.133 us; speedup 1.0000x reference)
//
#include <hip/hip_runtime.h>
#include <hip/hip_bf16.h>
#include <stdint.h>

// Problem constants
#define BB  2
#define SS  4096
#define EE  512
#define HH  8
#define HDD 64
#define MM  (BB*SS)   // 8192
#define NT  (SS/64)   // 64 k-tiles
#define NTH (NT/2)    // 32 k-tiles per split-half

typedef __bf16 bf16;
typedef __attribute__((ext_vector_type(8))) __bf16 bf16x8;
typedef __attribute__((ext_vector_type(4))) __bf16 bf16x4;
typedef __attribute__((ext_vector_type(4))) float  f32x4;
typedef __attribute__((ext_vector_type(16))) float f32x16;

#if __has_builtin(__builtin_amdgcn_exp2f)
#define EXP2F(x) __builtin_amdgcn_exp2f(x)
#else
#define EXP2F(x) __builtin_exp2f(x)
#endif

static __device__ __forceinline__ f32x4 mfma16(bf16x8 a, bf16x8 b, f32x4 c) {
    return __builtin_amdgcn_mfma_f32_16x16x32_bf16(a, b, c, 0, 0, 0);
}
static __device__ __forceinline__ f32x16 mfma32(bf16x8 a, bf16x8 b, f32x16 c) {
    return __builtin_amdgcn_mfma_f32_32x32x16_bf16(a, b, c, 0, 0, 0);
}
static __device__ __forceinline__ bf16x8 ldg8(const bf16* p) {
    return *reinterpret_cast<const bf16x8*>(p);
}
static __device__ __forceinline__ bf16x8 cvt8(float4 a, float4 b) {
    bf16x8 o;
    o[0]=(bf16)a.x; o[1]=(bf16)a.y; o[2]=(bf16)a.z; o[3]=(bf16)a.w;
    o[4]=(bf16)b.x; o[5]=(bf16)b.y; o[6]=(bf16)b.z; o[7]=(bf16)b.w;
    return o;
}
static __device__ __forceinline__ uint32_t pk2(float a, float b) {
    union { __bf16 h[2]; uint32_t u; } x;
    x.h[0] = (__bf16)a; x.h[1] = (__bf16)b; return x.u;
}
static __device__ __forceinline__ bf16x8 frag4(uint32_t a, uint32_t b, uint32_t c, uint32_t d) {
    union { uint32_t u[4]; bf16x8 v; } x;
    x.u[0]=a; x.u[1]=b; x.u[2]=c; x.u[3]=d; return x.v;
}
// async global->LDS, 16B per lane; lds dest is wave-uniform base (HW adds lane*16)
static __device__ __forceinline__ void gload16(const bf16* g, char* lds) {
    __builtin_amdgcn_global_load_lds(
        (const __attribute__((address_space(1))) void*)g,
        (__attribute__((address_space(3))) void*)lds,
        16, 0, 0);
}

// ---------------------------------------------------------------- mask pack
// mask[b,1,q,k] int32 -> bit words laid out tile-major: MW[(b*NT + kt)*S + q]
__global__ void k_pack_mask(const int* __restrict__ mask,
                            unsigned long long* __restrict__ out) {
    const int nwords = BB * SS * NT;   // 524288
    int lane = threadIdx.x & 63;
    int wid  = blockIdx.x * (blockDim.x >> 6) + (threadIdx.x >> 6);
    int nw   = gridDim.x * (blockDim.x >> 6);
    for (int w = wid; w < nwords; w += nw) {
        int v = mask[(size_t)w * 64 + lane];
        unsigned long long word = __ballot(v != 0);
        if (lane == 0) {
            int kt = w & (NT - 1);
            int q  = (w >> 6) & (SS - 1);
            int b  = w >> 18;
            out[((size_t)b * NT + kt) * SS + q] = word;
        }
    }
}

// ---------------------------------------------------------------- QKV GEMM
// LDS-staged, double-buffered, reg-staged fp32->bf16 convert.
// z=0: q -> QP [M,E]; z=1: k -> KP [M,E]; z=2: v -> VT [B,E,S]
__global__ __launch_bounds__(256) void k_gemm_qkv(
    const float* __restrict__ XQ, const float* __restrict__ XK, const float* __restrict__ XV,
    const float* __restrict__ WQ, const float* __restrict__ WK, const float* __restrict__ WV,
    bf16* __restrict__ QP, bf16* __restrict__ KP, bf16* __restrict__ VT)
{
    const int z = blockIdx.z;
    const float* A = (z == 0) ? XQ : (z == 1) ? XK : XV;
    const float* W = (z == 0) ? WQ : (z == 1) ? WK : WV;

    const int tid = threadIdx.x;
    const int lane = tid & 63, wave = tid >> 6;
    const int lr = lane & 15, lg = lane >> 4;
    const int m0 = blockIdx.y * 128, n0 = blockIdx.x * 128;

    __shared__ alignas(16) bf16 As[2][128 * 32];
    __shared__ alignas(16) bf16 Bs[2][128 * 32];

    // staging: thread covers half a row (16 f32 = 2 chunks of 16B bf16)
    const int srow = tid >> 1, shalf = tid & 1;
    const float* Ag = A + (size_t)(m0 + srow) * EE + shalf * 16;
    const float* Wg = W + (size_t)(n0 + srow) * EE + shalf * 16;
    const int sw0 = srow * 64 + ((((shalf * 2)    ) ^ ((srow >> 1) & 3)) << 4);
    const int sw1 = srow * 64 + ((((shalf * 2) + 1) ^ ((srow >> 1) & 3)) << 4);

    // fragment read byte offsets (chunk ^= (row>>1)&3 swizzle -> 2-way, free)
    int aoff[4], boff[4];
    {
        const int mw = (wave >> 1) * 64, nw = (wave & 1) * 64;
        #pragma unroll
        for (int i = 0; i < 4; ++i) { int r = mw + i*16 + lr; aoff[i] = r*64 + ((lg ^ ((r>>1)&3)) << 4); }
        #pragma unroll
        for (int j = 0; j < 4; ++j) { int r = nw + j*16 + lr; boff[j] = r*64 + ((lg ^ ((r>>1)&3)) << 4); }
    }

    f32x4 acc[4][4] = {};
    float4 sa0, sa1, sa2, sa3, sb0, sb1, sb2, sb3;

    sa0 = *(const float4*)(Ag);     sa1 = *(const float4*)(Ag + 4);
    sa2 = *(const float4*)(Ag + 8); sa3 = *(const float4*)(Ag + 12);
    sb0 = *(const float4*)(Wg);     sb1 = *(const float4*)(Wg + 4);
    sb2 = *(const float4*)(Wg + 8); sb3 = *(const float4*)(Wg + 12);
    {
        char* ab = (char*)As[0]; char* bb = (char*)Bs[0];
        *(bf16x8*)(ab + sw0) = cvt8(sa0, sa1);
        *(bf16x8*)(ab + sw1) = cvt8(sa2, sa3);
        *(bf16x8*)(bb + sw0) = cvt8(sb0, sb1);
        *(bf16x8*)(bb + sw1) = cvt8(sb2, sb3);
    }
    __syncthreads();

    for (int kb = 0; kb < 16; ++kb) {
        if (kb + 1 < 16) {   // T14: issue next-step loads before compute
            const float* An = Ag + (kb + 1) * 32;
            const float* Wn = Wg + (kb + 1) * 32;
            sa0 = *(const float4*)(An);     sa1 = *(const float4*)(An + 4);
            sa2 = *(const float4*)(An + 8); sa3 = *(const float4*)(An + 12);
            sb0 = *(const float4*)(Wn);     sb1 = *(const float4*)(Wn + 4);
            sb2 = *(const float4*)(Wn + 8); sb3 = *(const float4*)(Wn + 12);
        }
        const char* ab = (const char*)As[kb & 1];
        const char* bb = (const char*)Bs[kb & 1];
        bf16x8 af[4], bw[4];
        #pragma unroll
        for (int i = 0; i < 4; ++i) af[i] = *(const bf16x8*)(ab + aoff[i]);
        #pragma unroll
        for (int j = 0; j < 4; ++j) bw[j] = *(const bf16x8*)(bb + boff[j]);
        #pragma unroll
        for (int i = 0; i < 4; ++i)
            #pragma unroll
            for (int j = 0; j < 4; ++j)
                acc[i][j] = mfma16(af[i], bw[j], acc[i][j]);
        __syncthreads();
        if (kb + 1 < 16) {
            char* ab2 = (char*)As[(kb + 1) & 1]; char* bb2 = (char*)Bs[(kb + 1) & 1];
            *(bf16x8*)(ab2 + sw0) = cvt8(sa0, sa1);
            *(bf16x8*)(ab2 + sw1) = cvt8(sa2, sa3);
            *(bf16x8*)(bb2 + sw0) = cvt8(sb0, sb1);
            *(bf16x8*)(bb2 + sw1) = cvt8(sb2, sb3);
        }
        __syncthreads();
    }

    const int mw0 = m0 + (wave >> 1) * 64, nw0 = n0 + (wave & 1) * 64;
    if (z < 2) {
        bf16* O = (z == 0) ? QP : KP;
        #pragma unroll
        for (int i = 0; i < 4; ++i)
            #pragma unroll
            for (int j = 0; j < 4; ++j)
                #pragma unroll
                for (int r = 0; r < 4; ++r) {
                    int m = mw0 + i*16 + lg*4 + r;
                    int n = nw0 + j*16 + lr;
                    O[(size_t)m * EE + n] = (bf16)acc[i][j][r];
                }
    } else {
        #pragma unroll
        for (int i = 0; i < 4; ++i) {
            int mrow = mw0 + i*16 + lg*4;
            int bidx = mrow >> 12;
            int s0   = mrow & (SS - 1);
            #pragma unroll
            for (int j = 0; j < 4; ++j) {
                int n = nw0 + j*16 + lr;
                bf16x4 v = { (bf16)acc[i][j][0], (bf16)acc[i][j][1],
                             (bf16)acc[i][j][2], (bf16)acc[i][j][3] };
                *reinterpret_cast<bf16x4*>(VT + ((size_t)bidx * EE + n) * SS + s0) = v;
            }
        }
    }
}

// ---------------------------------------------------------------- attention
// Swapped-QK 32x32 MFMA flash attention, no-max softmax, KV-split x2.
// global_load_lds staging (swizzle-via-source), two-pass k-halves,
// register-dieted to fit 4 waves/SIMD (launch_bounds(256,4)).
// grid (S/128, H, B*2), block 256 (4 waves); wave owns 32 q-rows.
__global__ __launch_bounds__(256, 4) void k_attn(
    const bf16* __restrict__ QP, const bf16* __restrict__ KP,
    const bf16* __restrict__ VT, const unsigned long long* __restrict__ MW,
    float* __restrict__ OP, float* __restrict__ LP)
{
    const int zz = blockIdx.z;
    const int b = zz >> 1, half = zz & 1;
    const int h = blockIdx.y;
    const int tid  = threadIdx.x;
    const int lane = tid & 63;
    const int wave = tid >> 6;
    const int lq = lane & 31;
    const int hi = lane >> 5;
    const int q0 = blockIdx.x * 128 + wave * 32;
    const int kt0 = half * NTH;
    constexpr float SC = 0.044194173824159216f * 1.4426950408889634f; // 1/sqrt(512)*log2(e)

    // per buffer: K tile 8KB @ [0,8192), V tile 8KB @ [8192,16384)
    __shared__ alignas(16) char smem[2][16384];

    // ---- Q fragments (B-operand), prescaled by SC once.
    const bf16* Qb = QP + (size_t)(b * SS + q0 + lq) * EE + h * HDD + hi * 8;
    bf16x8 qf[4];
    #pragma unroll
    for (int dc = 0; dc < 4; ++dc) {
        bf16x8 t = ldg8(Qb + dc * 16);
        bf16x8 o;
        #pragma unroll
        for (int j = 0; j < 8; ++j) o[j] = (bf16)((float)t[j] * SC);
        qf[dc] = o;
    }

    // ---- global_load_lds staging geometry (see round-7 comment; unchanged)
    const int srow = wave * 16 + (lane >> 3);
    const int sch  = (lane & 7) ^ (srow & 7);
    const bf16* Kg = KP + ((size_t)(b * SS) + kt0 * 64 + srow) * EE + h * HDD + (sch << 3);
    const bf16* Vg = VT + ((size_t)(b * EE) + h * HDD + srow) * SS + kt0 * 64 + (sch << 3);

    // ---- fragment read chunk offsets: sw[dc] = ((dc*2+hi) ^ (lq&7)) * 16
    // row bases via immediates: K rowA = lq*128, K rowB = +4096,
    // V rowA = +8192, V rowB = +12288 (V chunks: pass A sw0/sw1, pass B sw2/sw3)
    int sw0 = (((0 + hi) ^ (lq & 7)) << 4);
    int sw1 = (((2 + hi) ^ (lq & 7)) << 4);
    int sw2 = (((4 + hi) ^ (lq & 7)) << 4);
    int sw3 = (((6 + hi) ^ (lq & 7)) << 4);
    const char* kb0 = smem[0] + lq * 128;
    const char* kb1 = smem[1] + lq * 128;

    const unsigned long long* Mb = MW + (size_t)b * NT * SS + (size_t)kt0 * SS + (q0 + lq);

    f32x16 o0 = {}, o1 = {};   // O[q=crow(r,hi)][d = dblk*32 + lq]
    float lsum = 0.f;

#define STAGE(buf, t) do {                                        \
        const bf16* kg_ = Kg + (size_t)(t) * 64 * EE;             \
        const bf16* vg_ = Vg + (t) * 64;                          \
        char* kb_ = smem[buf] + wave * 2048;                      \
        char* vb_ = smem[buf] + 8192 + wave * 2048;               \
        gload16(kg_,          kb_);                               \
        gload16(kg_ + 8 * EE, kb_ + 1024);                        \
        gload16(vg_,          vb_);                               \
        gload16(vg_ + 8 * SS, vb_ + 1024);                        \
    } while (0)

    // ---- prologue: stage tile 0
    STAGE(0, 0);
    asm volatile("s_waitcnt vmcnt(0)" ::: "memory");
    __syncthreads();

    for (int kt = 0; kt < NTH; ++kt) {
        // issue next-tile async loads into the buffer freed at last barrier
        if (kt + 1 < NTH) STAGE((kt & 1) ^ 1, kt + 1);

        const char* base = (kt & 1) ? kb1 : kb0;
        const unsigned long long w = Mb[(size_t)kt * SS];

        // ================= PASS A: k-rows 0..31 of the tile =================
        {
            bf16x8 kf0 = *(const bf16x8*)(base + sw0);
            bf16x8 kf1 = *(const bf16x8*)(base + sw1);
            bf16x8 kf2 = *(const bf16x8*)(base + sw2);
            bf16x8 kf3 = *(const bf16x8*)(base + sw3);
            f32x16 s = {};
            __builtin_amdgcn_s_setprio(1);
            s = mfma32(kf0, qf[0], s);
            s = mfma32(kf1, qf[1], s);
            s = mfma32(kf2, qf[2], s);
            s = mfma32(kf3, qf[3], s);
            __builtin_amdgcn_s_setprio(0);

            const uint32_t hw = (uint32_t)(w >> (4 * hi));
            uint32_t wA[8];
            #pragma unroll
            for (int i = 0; i < 8; ++i) {
                const int r0 = 2*i, r1 = 2*i+1;
                const int pos0 = (r0 & 3) + 8 * (r0 >> 2);
                const int pos1 = (r1 & 3) + 8 * (r1 >> 2);
                float e0 = EXP2F(s[r0]);
                float e1 = EXP2F(s[r1]);
                e0 = (hw & (1u << pos0)) ? e0 : 0.f;
                e1 = (hw & (1u << pos1)) ? e1 : 0.f;
                lsum += e0 + e1;
                wA[i] = pk2(e0, e1);
            }
            uint32_t ra0 = __shfl_xor((int)(hi ? wA[0] : wA[2]), 32);
            uint32_t ra1 = __shfl_xor((int)(hi ? wA[1] : wA[3]), 32);
            uint32_t ra2 = __shfl_xor((int)(hi ? wA[4] : wA[6]), 32);
            uint32_t ra3 = __shfl_xor((int)(hi ? wA[5] : wA[7]), 32);
            bf16x8 pa0 = frag4(hi ? ra0 : wA[0], hi ? ra1 : wA[1],
                               hi ? wA[2] : ra0, hi ? wA[3] : ra1);
            bf16x8 pa1 = frag4(hi ? ra2 : wA[4], hi ? ra3 : wA[5],
                               hi ? wA[6] : ra2, hi ? wA[7] : ra3);

            bf16x8 v00 = *(const bf16x8*)(base + 8192  + sw0);
            bf16x8 v01 = *(const bf16x8*)(base + 8192  + sw1);
            bf16x8 v10 = *(const bf16x8*)(base + 12288 + sw0);
            bf16x8 v11 = *(const bf16x8*)(base + 12288 + sw1);
            __builtin_amdgcn_s_setprio(1);
            o0 = mfma32(pa0, v00, o0);
            o0 = mfma32(pa1, v01, o0);
            o1 = mfma32(pa0, v10, o1);
            o1 = mfma32(pa1, v11, o1);
            __builtin_amdgcn_s_setprio(0);
        }

        // ================= PASS B: k-rows 32..63 of the tile ================
        {
            bf16x8 kf0 = *(const bf16x8*)(base + 4096 + sw0);
            bf16x8 kf1 = *(const bf16x8*)(base + 4096 + sw1);
            bf16x8 kf2 = *(const bf16x8*)(base + 4096 + sw2);
            bf16x8 kf3 = *(const bf16x8*)(base + 4096 + sw3);
            f32x16 s = {};
            __builtin_amdgcn_s_setprio(1);
            s = mfma32(kf0, qf[0], s);
            s = mfma32(kf1, qf[1], s);
            s = mfma32(kf2, qf[2], s);
            s = mfma32(kf3, qf[3], s);
            __builtin_amdgcn_s_setprio(0);

            const uint32_t hw = (uint32_t)(w >> (32 + 4 * hi));
            uint32_t wB[8];
            #pragma unroll
            for (int i = 0; i < 8; ++i) {
                const int r0 = 2*i, r1 = 2*i+1;
                const int pos0 = (r0 & 3) + 8 * (r0 >> 2);
                const int pos1 = (r1 & 3) + 8 * (r1 >> 2);
                float e0 = EXP2F(s[r0]);
                float e1 = EXP2F(s[r1]);
                e0 = (hw & (1u << pos0)) ? e0 : 0.f;
                e1 = (hw & (1u << pos1)) ? e1 : 0.f;
                lsum += e0 + e1;
                wB[i] = pk2(e0, e1);
            }
            uint32_t rb0 = __shfl_xor((int)(hi ? wB[0] : wB[2]), 32);
            uint32_t rb1 = __shfl_xor((int)(hi ? wB[1] : wB[3]), 32);
            uint32_t rb2 = __shfl_xor((int)(hi ? wB[4] : wB[6]), 32);
            uint32_t rb3 = __shfl_xor((int)(hi ? wB[5] : wB[7]), 32);
            bf16x8 pb0 = frag4(hi ? rb0 : wB[0], hi ? rb1 : wB[1],
                               hi ? wB[2] : rb0, hi ? wB[3] : rb1);
            bf16x8 pb1 = frag4(hi ? rb2 : wB[4], hi ? rb3 : wB[5],
                               hi ? wB[6] : rb2, hi ? wB[7] : rb3);

            bf16x8 v00 = *(const bf16x8*)(base + 8192  + sw2);
            bf16x8 v01 = *(const bf16x8*)(base + 8192  + sw3);
            bf16x8 v10 = *(const bf16x8*)(base + 12288 + sw2);
            bf16x8 v11 = *(const bf16x8*)(base + 12288 + sw3);
            __builtin_amdgcn_s_setprio(1);
            o0 = mfma32(pb0, v00, o0);
            o0 = mfma32(pb1, v01, o0);
            o1 = mfma32(pb0, v10, o1);
            o1 = mfma32(pb1, v11, o1);
            __builtin_amdgcn_s_setprio(0);
        }

        // ---- next-tile loads have landed (issued a full tile ago); release buf
        asm volatile("s_waitcnt vmcnt(0)" ::: "memory");
        __syncthreads();
    }
#undef STAGE

    // ---- partial row-sum: this lane + partner cover this half's k range
    float ltot = lsum + __shfl_xor(lsum, 32);

    // ---- store raw partials; out-proj staging normalizes
    float* OPb = OP + ((((size_t)half * BB + b) * HH + h) * SS + q0) * 64;
    float* LPb = LP + (((size_t)half * BB + b) * HH + h) * SS + q0;
    #pragma unroll
    for (int r = 0; r < 16; ++r) {
        int qr = (r & 3) + 8 * (r >> 2) + 4 * hi;
        OPb[(size_t)qr * 64 + lq]      = o0[r];
        OPb[(size_t)qr * 64 + 32 + lq] = o1[r];
    }
    if (hi == 0) LPb[lq] = ltot;   // lane lq holds q-row lq's partial sum
}

// ---------------------------------------------------------------- out proj
// LDS-staged; A is built on the fly from attention partials:
// A[m][e] = (OP0[b,h,q,d] + OP1[b,h,q,d]) / (LP0+LP1), converted to bf16
// during staging (combine kernel fused away). W fp32, out fp32 + bias.
__global__ __launch_bounds__(256) void k_gemm_out(
    const float* __restrict__ OP, const float* __restrict__ LP,
    const float* __restrict__ WO, const float* __restrict__ bo,
    float* __restrict__ out)
{
    const int tid = threadIdx.x;
    const int lane = tid & 63, wave = tid >> 6;
    const int lr = lane & 15, lg = lane >> 4;
    const int m0 = blockIdx.y * 128, n0 = blockIdx.x * 128;

    __shared__ alignas(16) bf16 As[2][128 * 32];
    __shared__ alignas(16) bf16 Bs[2][128 * 32];

    const int srow = tid >> 1, shalf = tid & 1;
    const int m  = m0 + srow;
    const int bq = m >> 12;            // batch
    const int qq = m & (SS - 1);       // sequence pos
    const size_t HALFO = (size_t)BB * HH * SS * 64;
    const size_t HALFL = (size_t)BB * HH * SS;
    const float* Wg = WO + (size_t)(n0 + srow) * EE + shalf * 16;
    const int sw0 = srow * 64 + ((((shalf * 2)    ) ^ ((srow >> 1) & 3)) << 4);
    const int sw1 = srow * 64 + ((((shalf * 2) + 1) ^ ((srow >> 1) & 3)) << 4);

    int aoff[4], boff[4];
    {
        const int mw = (wave >> 1) * 64, nw = (wave & 1) * 64;
        #pragma unroll
        for (int i = 0; i < 4; ++i) { int r = mw + i*16 + lr; aoff[i] = r*64 + ((lg ^ ((r>>1)&3)) << 4); }
        #pragma unroll
        for (int j = 0; j < 4; ++j) { int r = nw + j*16 + lr; boff[j] = r*64 + ((lg ^ ((r>>1)&3)) << 4); }
    }

    // fused A-stage: load OP halves + LP, normalize, convert
#define LOAD_A(kb, oa0, oa1)  do {                                            \
        const int e0_ = (kb) * 32 + shalf * 16;                               \
        const int hh_ = e0_ >> 6, d0_ = e0_ & 63;                             \
        const size_t lo_ = ((size_t)(bq * HH + hh_)) * SS + qq;               \
        const float* p0_ = OP + lo_ * 64 + d0_;                               \
        const float* p1_ = p0_ + HALFO;                                       \
        float inv_ = 1.0f / (LP[lo_] + LP[HALFL + lo_]);                      \
        float4 a0_ = *(const float4*)(p0_);      float4 b0_ = *(const float4*)(p1_);      \
        float4 a1_ = *(const float4*)(p0_ + 4);  float4 b1_ = *(const float4*)(p1_ + 4);  \
        float4 a2_ = *(const float4*)(p0_ + 8);  float4 b2_ = *(const float4*)(p1_ + 8);  \
        float4 a3_ = *(const float4*)(p0_ + 12); float4 b3_ = *(const float4*)(p1_ + 12); \
        float4 c0_ = { (a0_.x + b0_.x) * inv_, (a0_.y + b0_.y) * inv_,        \
                       (a0_.z + b0_.z) * inv_, (a0_.w + b0_.w) * inv_ };      \
        float4 c1_ = { (a1_.x + b1_.x) * inv_, (a1_.y + b1_.y) * inv_,        \
                       (a1_.z + b1_.z) * inv_, (a1_.w + b1_.w) * inv_ };      \
        float4 c2_ = { (a2_.x + b2_.x) * inv_, (a2_.y + b2_.y) * inv_,        \
                       (a2_.z + b2_.z) * inv_, (a2_.w + b2_.w) * inv_ };      \
        float4 c3_ = { (a3_.x + b3_.x) * inv_, (a3_.y + b3_.y) * inv_,        \
                       (a3_.z + b3_.z) * inv_, (a3_.w + b3_.w) * inv_ };      \
        oa0 = cvt8(c0_, c1_);  oa1 = cvt8(c2_, c3_);                          \
    } while (0)

    f32x4 acc[4][4] = {};
    bf16x8 qa0, qa1;
    float4 sb0, sb1, sb2, sb3;

    LOAD_A(0, qa0, qa1);
    sb0 = *(const float4*)(Wg);     sb1 = *(const float4*)(Wg + 4);
    sb2 = *(const float4*)(Wg + 8); sb3 = *(const float4*)(Wg + 12);
    {
        char* ab = (char*)As[0]; char* bb = (char*)Bs[0];
        *(bf16x8*)(ab + sw0) = qa0;
        *(bf16x8*)(ab + sw1) = qa1;
        *(bf16x8*)(bb + sw0) = cvt8(sb0, sb1);
        *(bf16x8*)(bb + sw1) = cvt8(sb2, sb3);
    }
    __syncthreads();

    for (int kb = 0; kb < 16; ++kb) {
        if (kb + 1 < 16) {
            LOAD_A(kb + 1, qa0, qa1);
            const float* Wn = Wg + (kb + 1) * 32;
            sb0 = *(const float4*)(Wn);     sb1 = *(const float4*)(Wn + 4);
            sb2 = *(const float4*)(Wn + 8); sb3 = *(const float4*)(Wn + 12);
        }
        const char* ab = (const char*)As[kb & 1];
        const char* bb = (const char*)Bs[kb & 1];
        bf16x8 af[4], bw[4];
        #pragma unroll
        for (int i = 0; i < 4; ++i) af[i] = *(const bf16x8*)(ab + aoff[i]);
        #pragma unroll
        for (int j = 0; j < 4; ++j) bw[j] = *(const bf16x8*)(bb + boff[j]);
        #pragma unroll
        for (int i = 0; i < 4; ++i)
            #pragma unroll
            for (int j = 0; j < 4; ++j)
                acc[i][j] = mfma16(af[i], bw[j], acc[i][j]);
        __syncthreads();
        if (kb + 1 < 16) {
            char* ab2 = (char*)As[(kb + 1) & 1]; char* bb2 = (char*)Bs[(kb + 1) & 1];
            *(bf16x8*)(ab2 + sw0) = qa0;
            *(bf16x8*)(ab2 + sw1) = qa1;
            *(bf16x8*)(bb2 + sw0) = cvt8(sb0, sb1);
            *(bf16x8*)(bb2 + sw1) = cvt8(sb2, sb3);
        }
        __syncthreads();
    }
#undef LOAD_A

    const int mw0 = m0 + (wave >> 1) * 64, nw0 = n0 + (wave & 1) * 64;
    #pragma unroll
    for (int i = 0; i < 4; ++i)
        #pragma unroll
        for (int j = 0; j < 4; ++j)
            #pragma unroll
            for (int r = 0; r < 4; ++r) {
                int mm = mw0 + i*16 + lg*4 + r;
                int nn = nw0 + j*16 + lr;
                out[(size_t)mm * EE + nn] = acc[i][j][r] + bo[nn];
            }
}

// ---------------------------------------------------------------- launch
extern "C" void kernel_launch(void* const* d_in, const int* in_sizes, int n_in,
                              void* d_out, int out_size, void* d_ws, size_t ws_size,
                              hipStream_t stream) {
    const float* values = (const float*)d_in[0];
    const float* keys   = (const float*)d_in[1];
    const float* query  = (const float*)d_in[2];
    const int*   mask   = (const int*)d_in[3];
    const float* Wv     = (const float*)d_in[4];
    const float* Wk     = (const float*)d_in[5];
    const float* Wq     = (const float*)d_in[6];
    const float* Wo     = (const float*)d_in[7];
    const float* bo     = (const float*)d_in[8];
    float* out = (float*)d_out;

    char* ws = (char*)d_ws;
    const size_t ACT = (size_t)MM * EE;   // 4194304 elems
    bf16* QP = (bf16*)ws;
    bf16* KP = QP + ACT;
    bf16* VT = KP + ACT;
    bf16* AO = VT + ACT;                                        // (unused now)
    unsigned long long* MW = (unsigned long long*)(AO + ACT);   // 524288 words
    float* OP = (float*)(MW + (size_t)BB * SS * NT);            // 2 * 4.19M f32
    float* LP = OP + 2 * ACT;                                   // 2 * 65536 f32
    // total: 32MB + 4MB + 33.5MB + 0.5MB = ~70MB

    k_pack_mask<<<1024, 256, 0, stream>>>(mask, MW);
    k_gemm_qkv<<<dim3(EE/128, MM/128, 3), 256, 0, stream>>>(
        query, keys, values, Wq, Wk, Wv, QP, KP, VT);
    k_attn<<<dim3(SS/128, HH, BB*2), 256, 0, stream>>>(QP, KP, VT, MW, OP, LP);
    k_gemm_out<<<dim3(EE/128, MM/128, 1), 256, 0, stream>>>(OP, LP, Wo, bo, out);
}

// Round 9
// 210.764 us; speedup vs baseline: 1.1963x; 1.1963x over previous
//
#include <hip/hip_runtime.h>
#include <hip/hip_bf16.h>
#include <stdint.h>

// Problem constants
#define BB  2
#define SS  4096
#define EE  512
#define HH  8
#define HDD 64
#define MM  (BB*SS)   // 8192
#define NT  (SS/64)   // 64 k-tiles
#define NTH (NT/2)    // 32 k-tiles per split-half

typedef __bf16 bf16;
typedef __attribute__((ext_vector_type(8))) __bf16 bf16x8;
typedef __attribute__((ext_vector_type(4))) __bf16 bf16x4;
typedef __attribute__((ext_vector_type(4))) float  f32x4;
typedef __attribute__((ext_vector_type(16))) float f32x16;

#if __has_builtin(__builtin_amdgcn_exp2f)
#define EXP2F(x) __builtin_amdgcn_exp2f(x)
#else
#define EXP2F(x) __builtin_exp2f(x)
#endif

static __device__ __forceinline__ f32x4 mfma16(bf16x8 a, bf16x8 b, f32x4 c) {
    return __builtin_amdgcn_mfma_f32_16x16x32_bf16(a, b, c, 0, 0, 0);
}
static __device__ __forceinline__ f32x16 mfma32(bf16x8 a, bf16x8 b, f32x16 c) {
    return __builtin_amdgcn_mfma_f32_32x32x16_bf16(a, b, c, 0, 0, 0);
}
static __device__ __forceinline__ bf16x8 ldg8(const bf16* p) {
    return *reinterpret_cast<const bf16x8*>(p);
}
static __device__ __forceinline__ bf16x8 cvt8(float4 a, float4 b) {
    bf16x8 o;
    o[0]=(bf16)a.x; o[1]=(bf16)a.y; o[2]=(bf16)a.z; o[3]=(bf16)a.w;
    o[4]=(bf16)b.x; o[5]=(bf16)b.y; o[6]=(bf16)b.z; o[7]=(bf16)b.w;
    return o;
}
static __device__ __forceinline__ uint32_t pk2(float a, float b) {
    union { __bf16 h[2]; uint32_t u; } x;
    x.h[0] = (__bf16)a; x.h[1] = (__bf16)b; return x.u;
}
static __device__ __forceinline__ bf16x8 frag4(uint32_t a, uint32_t b, uint32_t c, uint32_t d) {
    union { uint32_t u[4]; bf16x8 v; } x;
    x.u[0]=a; x.u[1]=b; x.u[2]=c; x.u[3]=d; return x.v;
}
// async global->LDS, 16B per lane; lds dest is wave-uniform base (HW adds lane*16)
static __device__ __forceinline__ void gload16(const bf16* g, char* lds) {
    __builtin_amdgcn_global_load_lds(
        (const __attribute__((address_space(1))) void*)g,
        (__attribute__((address_space(3))) void*)lds,
        16, 0, 0);
}

// ---------------------------------------------------------------- QKV GEMM + mask pack
// grid (4, 64, 4): z==0 -> mask-pack role (dispatched FIRST, overlaps the GEMM
// blocks on the HBM pipe while they are compute/L2-bound);
// z==1..3 -> GEMM role (z-1 = q/k/v).
// GEMM: LDS-staged, double-buffered, reg-staged fp32->bf16 convert.
// q -> QP [M,E]; k -> KP [M,E]; v -> VT [B,E,S]
__global__ __launch_bounds__(256) void k_gemm_qkv(
    const float* __restrict__ XQ, const float* __restrict__ XK, const float* __restrict__ XV,
    const float* __restrict__ WQ, const float* __restrict__ WK, const float* __restrict__ WV,
    bf16* __restrict__ QP, bf16* __restrict__ KP, bf16* __restrict__ VT,
    const int* __restrict__ mask, unsigned long long* __restrict__ MW)
{
    const int tid = threadIdx.x;
    const int lane = tid & 63, wave = tid >> 6;

    if (blockIdx.z == 0) {
        // ---- mask pack role: mask[b,1,q,k] -> bit words MW[(b*NT+kt)*S + q]
        // 256 blocks * 4 waves = 1024 wave-ids; 8-way batched loads for MLP.
        const int nwords = BB * SS * NT;   // 524288
        const int wid = (blockIdx.y * 4 + blockIdx.x) * 4 + wave;  // 0..1023
        const int nw  = 1024;
        for (int w0 = wid * 8; w0 < nwords; w0 += nw * 8) {
            int v[8];
            #pragma unroll
            for (int j = 0; j < 8; ++j)
                v[j] = mask[(size_t)(w0 + j) * 64 + lane];
            #pragma unroll
            for (int j = 0; j < 8; ++j) {
                unsigned long long word = __ballot(v[j] != 0);
                if (lane == 0) {
                    int w  = w0 + j;
                    int kt = w & (NT - 1);
                    int q  = (w >> 6) & (SS - 1);
                    int b  = w >> 18;
                    MW[((size_t)b * NT + kt) * SS + q] = word;
                }
            }
        }
        return;
    }

    const int z = blockIdx.z - 1;
    const float* A = (z == 0) ? XQ : (z == 1) ? XK : XV;
    const float* W = (z == 0) ? WQ : (z == 1) ? WK : WV;

    const int lr = lane & 15, lg = lane >> 4;
    const int m0 = blockIdx.y * 128, n0 = blockIdx.x * 128;

    __shared__ alignas(16) bf16 As[2][128 * 32];
    __shared__ alignas(16) bf16 Bs[2][128 * 32];

    // staging: thread covers half a row (16 f32 = 2 chunks of 16B bf16)
    const int srow = tid >> 1, shalf = tid & 1;
    const float* Ag = A + (size_t)(m0 + srow) * EE + shalf * 16;
    const float* Wg = W + (size_t)(n0 + srow) * EE + shalf * 16;
    const int sw0 = srow * 64 + ((((shalf * 2)    ) ^ ((srow >> 1) & 3)) << 4);
    const int sw1 = srow * 64 + ((((shalf * 2) + 1) ^ ((srow >> 1) & 3)) << 4);

    // fragment read byte offsets (chunk ^= (row>>1)&3 swizzle -> 2-way, free)
    int aoff[4], boff[4];
    {
        const int mw = (wave >> 1) * 64, nw = (wave & 1) * 64;
        #pragma unroll
        for (int i = 0; i < 4; ++i) { int r = mw + i*16 + lr; aoff[i] = r*64 + ((lg ^ ((r>>1)&3)) << 4); }
        #pragma unroll
        for (int j = 0; j < 4; ++j) { int r = nw + j*16 + lr; boff[j] = r*64 + ((lg ^ ((r>>1)&3)) << 4); }
    }

    f32x4 acc[4][4] = {};
    float4 sa0, sa1, sa2, sa3, sb0, sb1, sb2, sb3;

    sa0 = *(const float4*)(Ag);     sa1 = *(const float4*)(Ag + 4);
    sa2 = *(const float4*)(Ag + 8); sa3 = *(const float4*)(Ag + 12);
    sb0 = *(const float4*)(Wg);     sb1 = *(const float4*)(Wg + 4);
    sb2 = *(const float4*)(Wg + 8); sb3 = *(const float4*)(Wg + 12);
    {
        char* ab = (char*)As[0]; char* bb = (char*)Bs[0];
        *(bf16x8*)(ab + sw0) = cvt8(sa0, sa1);
        *(bf16x8*)(ab + sw1) = cvt8(sa2, sa3);
        *(bf16x8*)(bb + sw0) = cvt8(sb0, sb1);
        *(bf16x8*)(bb + sw1) = cvt8(sb2, sb3);
    }
    __syncthreads();

    for (int kb = 0; kb < 16; ++kb) {
        if (kb + 1 < 16) {   // T14: issue next-step loads before compute
            const float* An = Ag + (kb + 1) * 32;
            const float* Wn = Wg + (kb + 1) * 32;
            sa0 = *(const float4*)(An);     sa1 = *(const float4*)(An + 4);
            sa2 = *(const float4*)(An + 8); sa3 = *(const float4*)(An + 12);
            sb0 = *(const float4*)(Wn);     sb1 = *(const float4*)(Wn + 4);
            sb2 = *(const float4*)(Wn + 8); sb3 = *(const float4*)(Wn + 12);
        }
        const char* ab = (const char*)As[kb & 1];
        const char* bb = (const char*)Bs[kb & 1];
        bf16x8 af[4], bw[4];
        #pragma unroll
        for (int i = 0; i < 4; ++i) af[i] = *(const bf16x8*)(ab + aoff[i]);
        #pragma unroll
        for (int j = 0; j < 4; ++j) bw[j] = *(const bf16x8*)(bb + boff[j]);
        #pragma unroll
        for (int i = 0; i < 4; ++i)
            #pragma unroll
            for (int j = 0; j < 4; ++j)
                acc[i][j] = mfma16(af[i], bw[j], acc[i][j]);
        __syncthreads();
        if (kb + 1 < 16) {
            char* ab2 = (char*)As[(kb + 1) & 1]; char* bb2 = (char*)Bs[(kb + 1) & 1];
            *(bf16x8*)(ab2 + sw0) = cvt8(sa0, sa1);
            *(bf16x8*)(ab2 + sw1) = cvt8(sa2, sa3);
            *(bf16x8*)(bb2 + sw0) = cvt8(sb0, sb1);
            *(bf16x8*)(bb2 + sw1) = cvt8(sb2, sb3);
        }
        __syncthreads();
    }

    const int mw0 = m0 + (wave >> 1) * 64, nw0 = n0 + (wave & 1) * 64;
    if (z < 2) {
        bf16* O = (z == 0) ? QP : KP;
        #pragma unroll
        for (int i = 0; i < 4; ++i)
            #pragma unroll
            for (int j = 0; j < 4; ++j)
                #pragma unroll
                for (int r = 0; r < 4; ++r) {
                    int m = mw0 + i*16 + lg*4 + r;
                    int n = nw0 + j*16 + lr;
                    O[(size_t)m * EE + n] = (bf16)acc[i][j][r];
                }
    } else {
        #pragma unroll
        for (int i = 0; i < 4; ++i) {
            int mrow = mw0 + i*16 + lg*4;
            int bidx = mrow >> 12;
            int s0   = mrow & (SS - 1);
            #pragma unroll
            for (int j = 0; j < 4; ++j) {
                int n = nw0 + j*16 + lr;
                bf16x4 v = { (bf16)acc[i][j][0], (bf16)acc[i][j][1],
                             (bf16)acc[i][j][2], (bf16)acc[i][j][3] };
                *reinterpret_cast<bf16x4*>(VT + ((size_t)bidx * EE + n) * SS + s0) = v;
            }
        }
    }
}

// ---------------------------------------------------------------- attention
// Swapped-QK 32x32 MFMA flash attention, no-max softmax, KV-split x2.
// global_load_lds staging (swizzle-via-source), two-pass k-halves.
// No setprio fences: both passes' chains are independent, let the
// scheduler interleave (exp of pass A under pass B's MFMAs).
// grid (S/128, H, B*2), block 256 (4 waves); wave owns 32 q-rows.
__global__ __launch_bounds__(256, 3) void k_attn(
    const bf16* __restrict__ QP, const bf16* __restrict__ KP,
    const bf16* __restrict__ VT, const unsigned long long* __restrict__ MW,
    float* __restrict__ OP, float* __restrict__ LP)
{
    const int zz = blockIdx.z;
    const int b = zz >> 1, half = zz & 1;
    const int h = blockIdx.y;
    const int tid  = threadIdx.x;
    const int lane = tid & 63;
    const int wave = tid >> 6;
    const int lq = lane & 31;
    const int hi = lane >> 5;
    const int q0 = blockIdx.x * 128 + wave * 32;
    const int kt0 = half * NTH;
    constexpr float SC = 0.044194173824159216f * 1.4426950408889634f; // 1/sqrt(512)*log2(e)

    // per buffer: K tile 8KB @ [0,8192), V tile 8KB @ [8192,16384)
    __shared__ alignas(16) char smem[2][16384];

    // ---- Q fragments (B-operand), prescaled by SC once.
    const bf16* Qb = QP + (size_t)(b * SS + q0 + lq) * EE + h * HDD + hi * 8;
    bf16x8 qf[4];
    #pragma unroll
    for (int dc = 0; dc < 4; ++dc) {
        bf16x8 t = ldg8(Qb + dc * 16);
        bf16x8 o;
        #pragma unroll
        for (int j = 0; j < 8; ++j) o[j] = (bf16)((float)t[j] * SC);
        qf[dc] = o;
    }

    // ---- global_load_lds staging geometry
    // wave w covers tile rows [16w, 16w+16): 2 insts (rows +0..7, +8..15).
    // lane l -> row 16w + 8j + (l>>3), chunk c = l&7. LDS layout row*128+c*16
    // == wave*2048 + j*1024 + l*16 (wave-linear). Read-side XOR swizzle
    // (c ^ row&7) realized by pre-XORing the global source column.
    const int srow = wave * 16 + (lane >> 3);
    const int sch  = (lane & 7) ^ (srow & 7);
    const bf16* Kg = KP + ((size_t)(b * SS) + kt0 * 64 + srow) * EE + h * HDD + (sch << 3);
    const bf16* Vg = VT + ((size_t)(b * EE) + h * HDD + srow) * SS + kt0 * 64 + (sch << 3);

    // ---- static per-lane fragment read offsets (chunk ^= row&7 swizzle)
    int koff[2][4];
    #pragma unroll
    for (int hf = 0; hf < 2; ++hf) {
        const int rk = lq + 32 * hf;
        #pragma unroll
        for (int dc = 0; dc < 4; ++dc)
            koff[hf][dc] = rk * 128 + (((dc * 2 + hi) ^ (rk & 7)) << 4);
    }

    const unsigned long long* Mb = MW + (size_t)b * NT * SS + (size_t)kt0 * SS + (q0 + lq);

    f32x16 o0 = {}, o1 = {};   // O[q=crow(r,hi)][d = dblk*32 + lq]
    float lsum = 0.f;

#define STAGE(buf, t) do {                                        \
        const bf16* kg_ = Kg + (size_t)(t) * 64 * EE;             \
        const bf16* vg_ = Vg + (t) * 64;                          \
        char* kb_ = smem[buf] + wave * 2048;                      \
        char* vb_ = smem[buf] + 8192 + wave * 2048;               \
        gload16(kg_,          kb_);                               \
        gload16(kg_ + 8 * EE, kb_ + 1024);                        \
        gload16(vg_,          vb_);                               \
        gload16(vg_ + 8 * SS, vb_ + 1024);                        \
    } while (0)

    // ---- prologue: stage tile 0
    STAGE(0, 0);
    asm volatile("s_waitcnt vmcnt(0)" ::: "memory");
    __syncthreads();

    for (int kt = 0; kt < NTH; ++kt) {
        const int cur = kt & 1;

        // issue next-tile async loads into the buffer freed at last barrier
        if (kt + 1 < NTH) STAGE(cur ^ 1, kt + 1);
        __builtin_amdgcn_sched_barrier(0);

        const char* rb = smem[cur];
        const unsigned long long w = Mb[(size_t)kt * SS];

        // ================= PASS A: k-rows 0..31 of the tile =================
        {
            bf16x8 kf[4];
            #pragma unroll
            for (int dc = 0; dc < 4; ++dc)
                kf[dc] = *reinterpret_cast<const bf16x8*>(rb + koff[0][dc]);
            f32x16 s = {};
            #pragma unroll
            for (int dc = 0; dc < 4; ++dc) s = mfma32(kf[dc], qf[dc], s);

            const uint32_t hw = (uint32_t)(w >> (4 * hi));
            uint32_t wA[8];
            #pragma unroll
            for (int i = 0; i < 8; ++i) {
                const int r0 = 2*i, r1 = 2*i+1;
                const int pos0 = (r0 & 3) + 8 * (r0 >> 2);
                const int pos1 = (r1 & 3) + 8 * (r1 >> 2);
                float e0 = EXP2F(s[r0]);
                float e1 = EXP2F(s[r1]);
                e0 = (hw & (1u << pos0)) ? e0 : 0.f;
                e1 = (hw & (1u << pos1)) ? e1 : 0.f;
                lsum += e0 + e1;
                wA[i] = pk2(e0, e1);
            }
            uint32_t ra0 = __shfl_xor((int)(hi ? wA[0] : wA[2]), 32);
            uint32_t ra1 = __shfl_xor((int)(hi ? wA[1] : wA[3]), 32);
            uint32_t ra2 = __shfl_xor((int)(hi ? wA[4] : wA[6]), 32);
            uint32_t ra3 = __shfl_xor((int)(hi ? wA[5] : wA[7]), 32);
            bf16x8 pa0 = frag4(hi ? ra0 : wA[0], hi ? ra1 : wA[1],
                               hi ? wA[2] : ra0, hi ? wA[3] : ra1);
            bf16x8 pa1 = frag4(hi ? ra2 : wA[4], hi ? ra3 : wA[5],
                               hi ? wA[6] : ra2, hi ? wA[7] : ra3);

            bf16x8 v00 = *reinterpret_cast<const bf16x8*>(rb + 8192 + koff[0][0]);
            bf16x8 v01 = *reinterpret_cast<const bf16x8*>(rb + 8192 + koff[0][1]);
            bf16x8 v10 = *reinterpret_cast<const bf16x8*>(rb + 8192 + koff[1][0]);
            bf16x8 v11 = *reinterpret_cast<const bf16x8*>(rb + 8192 + koff[1][1]);
            o0 = mfma32(pa0, v00, o0);
            o0 = mfma32(pa1, v01, o0);
            o1 = mfma32(pa0, v10, o1);
            o1 = mfma32(pa1, v11, o1);
        }

        // ================= PASS B: k-rows 32..63 of the tile ================
        {
            bf16x8 kf[4];
            #pragma unroll
            for (int dc = 0; dc < 4; ++dc)
                kf[dc] = *reinterpret_cast<const bf16x8*>(rb + koff[1][dc]);
            f32x16 s = {};
            #pragma unroll
            for (int dc = 0; dc < 4; ++dc) s = mfma32(kf[dc], qf[dc], s);

            const uint32_t hw = (uint32_t)(w >> (32 + 4 * hi));
            uint32_t wB[8];
            #pragma unroll
            for (int i = 0; i < 8; ++i) {
                const int r0 = 2*i, r1 = 2*i+1;
                const int pos0 = (r0 & 3) + 8 * (r0 >> 2);
                const int pos1 = (r1 & 3) + 8 * (r1 >> 2);
                float e0 = EXP2F(s[r0]);
                float e1 = EXP2F(s[r1]);
                e0 = (hw & (1u << pos0)) ? e0 : 0.f;
                e1 = (hw & (1u << pos1)) ? e1 : 0.f;
                lsum += e0 + e1;
                wB[i] = pk2(e0, e1);
            }
            uint32_t rb0 = __shfl_xor((int)(hi ? wB[0] : wB[2]), 32);
            uint32_t rb1 = __shfl_xor((int)(hi ? wB[1] : wB[3]), 32);
            uint32_t rb2 = __shfl_xor((int)(hi ? wB[4] : wB[6]), 32);
            uint32_t rb3 = __shfl_xor((int)(hi ? wB[5] : wB[7]), 32);
            bf16x8 pb0 = frag4(hi ? rb0 : wB[0], hi ? rb1 : wB[1],
                               hi ? wB[2] : rb0, hi ? wB[3] : rb1);
            bf16x8 pb1 = frag4(hi ? rb2 : wB[4], hi ? rb3 : wB[5],
                               hi ? wB[6] : rb2, hi ? wB[7] : rb3);

            bf16x8 v00 = *reinterpret_cast<const bf16x8*>(rb + 8192 + koff[0][2]);
            bf16x8 v01 = *reinterpret_cast<const bf16x8*>(rb + 8192 + koff[0][3]);
            bf16x8 v10 = *reinterpret_cast<const bf16x8*>(rb + 8192 + koff[1][2]);
            bf16x8 v11 = *reinterpret_cast<const bf16x8*>(rb + 8192 + koff[1][3]);
            o0 = mfma32(pb0, v00, o0);
            o0 = mfma32(pb1, v01, o0);
            o1 = mfma32(pb0, v10, o1);
            o1 = mfma32(pb1, v11, o1);
        }

        // ---- next-tile loads have landed (issued a full tile ago); release buf
        asm volatile("s_waitcnt vmcnt(0)" ::: "memory");
        __syncthreads();
    }
#undef STAGE

    // ---- partial row-sum: this lane + partner cover this half's k range
    float ltot = lsum + __shfl_xor(lsum, 32);

    // ---- store raw partials; combine kernel normalizes
    float* OPb = OP + ((((size_t)half * BB + b) * HH + h) * SS + q0) * 64;
    float* LPb = LP + (((size_t)half * BB + b) * HH + h) * SS + q0;
    #pragma unroll
    for (int r = 0; r < 16; ++r) {
        int qr = (r & 3) + 8 * (r >> 2) + 4 * hi;
        OPb[(size_t)qr * 64 + lq]      = o0[r];
        OPb[(size_t)qr * 64 + 32 + lq] = o1[r];
    }
    if (hi == 0) LPb[lq] = ltot;   // lane lq holds q-row lq's partial sum
}

// ---------------------------------------------------------------- combine
// AO[b,q,h*64+d] = (OP0 + OP1) / (LP0 + LP1), bf16
__global__ __launch_bounds__(256) void k_combine(
    const float* __restrict__ OP, const float* __restrict__ LP,
    bf16* __restrict__ AO)
{
    const int t = blockIdx.x * 256 + threadIdx.x;      // 2^20 threads
    const int dg = t & 15;
    const int q  = (t >> 4) & (SS - 1);
    const int hb = t >> 16;
    const int h  = hb & 7;
    const int b  = hb >> 3;
    const size_t HALFO = (size_t)BB * HH * SS * 64;
    const size_t HALFL = (size_t)BB * HH * SS;
    const size_t poff = ((((size_t)b * HH + h) * SS) + q) * 64 + dg * 4;
    const size_t loff = (((size_t)b * HH + h) * SS) + q;
    float4 oa = *(const float4*)(OP + poff);
    float4 ob = *(const float4*)(OP + HALFO + poff);
    float inv = 1.0f / (LP[loff] + LP[HALFL + loff]);
    bf16x4 o = { (bf16)((oa.x + ob.x) * inv), (bf16)((oa.y + ob.y) * inv),
                 (bf16)((oa.z + ob.z) * inv), (bf16)((oa.w + ob.w) * inv) };
    *reinterpret_cast<bf16x4*>(AO + ((size_t)(b * SS + q)) * EE + h * 64 + dg * 4) = o;
}

// ---------------------------------------------------------------- out proj
// LDS-staged; A is bf16 (AO), W fp32, out fp32 + bias.
__global__ __launch_bounds__(256) void k_gemm_out(
    const bf16* __restrict__ AO, const float* __restrict__ WO,
    const float* __restrict__ bo, float* __restrict__ out)
{
    const int tid = threadIdx.x;
    const int lane = tid & 63, wave = tid >> 6;
    const int lr = lane & 15, lg = lane >> 4;
    const int m0 = blockIdx.y * 128, n0 = blockIdx.x * 128;

    __shared__ alignas(16) bf16 As[2][128 * 32];
    __shared__ alignas(16) bf16 Bs[2][128 * 32];

    const int srow = tid >> 1, shalf = tid & 1;
    const bf16*  Ag = AO + (size_t)(m0 + srow) * EE + shalf * 16;
    const float* Wg = WO + (size_t)(n0 + srow) * EE + shalf * 16;
    const int sw0 = srow * 64 + ((((shalf * 2)    ) ^ ((srow >> 1) & 3)) << 4);
    const int sw1 = srow * 64 + ((((shalf * 2) + 1) ^ ((srow >> 1) & 3)) << 4);

    int aoff[4], boff[4];
    {
        const int mw = (wave >> 1) * 64, nw = (wave & 1) * 64;
        #pragma unroll
        for (int i = 0; i < 4; ++i) { int r = mw + i*16 + lr; aoff[i] = r*64 + ((lg ^ ((r>>1)&3)) << 4); }
        #pragma unroll
        for (int j = 0; j < 4; ++j) { int r = nw + j*16 + lr; boff[j] = r*64 + ((lg ^ ((r>>1)&3)) << 4); }
    }

    f32x4 acc[4][4] = {};
    bf16x8 qa0, qa1;
    float4 sb0, sb1, sb2, sb3;

    qa0 = ldg8(Ag); qa1 = ldg8(Ag + 8);
    sb0 = *(const float4*)(Wg);     sb1 = *(const float4*)(Wg + 4);
    sb2 = *(const float4*)(Wg + 8); sb3 = *(const float4*)(Wg + 12);
    {
        char* ab = (char*)As[0]; char* bb = (char*)Bs[0];
        *(bf16x8*)(ab + sw0) = qa0;
        *(bf16x8*)(ab + sw1) = qa1;
        *(bf16x8*)(bb + sw0) = cvt8(sb0, sb1);
        *(bf16x8*)(bb + sw1) = cvt8(sb2, sb3);
    }
    __syncthreads();

    for (int kb = 0; kb < 16; ++kb) {
        if (kb + 1 < 16) {
            const bf16*  An = Ag + (kb + 1) * 32;
            const float* Wn = Wg + (kb + 1) * 32;
            qa0 = ldg8(An); qa1 = ldg8(An + 8);
            sb0 = *(const float4*)(Wn);     sb1 = *(const float4*)(Wn + 4);
            sb2 = *(const float4*)(Wn + 8); sb3 = *(const float4*)(Wn + 12);
        }
        const char* ab = (const char*)As[kb & 1];
        const char* bb = (const char*)Bs[kb & 1];
        bf16x8 af[4], bw[4];
        #pragma unroll
        for (int i = 0; i < 4; ++i) af[i] = *(const bf16x8*)(ab + aoff[i]);
        #pragma unroll
        for (int j = 0; j < 4; ++j) bw[j] = *(const bf16x8*)(bb + boff[j]);
        #pragma unroll
        for (int i = 0; i < 4; ++i)
            #pragma unroll
            for (int j = 0; j < 4; ++j)
                acc[i][j] = mfma16(af[i], bw[j], acc[i][j]);
        __syncthreads();
        if (kb + 1 < 16) {
            char* ab2 = (char*)As[(kb + 1) & 1]; char* bb2 = (char*)Bs[(kb + 1) & 1];
            *(bf16x8*)(ab2 + sw0) = qa0;
            *(bf16x8*)(ab2 + sw1) = qa1;
            *(bf16x8*)(bb2 + sw0) = cvt8(sb0, sb1);
            *(bf16x8*)(bb2 + sw1) = cvt8(sb2, sb3);
        }
        __syncthreads();
    }

    const int mw0 = m0 + (wave >> 1) * 64, nw0 = n0 + (wave & 1) * 64;
    #pragma unroll
    for (int i = 0; i < 4; ++i)
        #pragma unroll
        for (int j = 0; j < 4; ++j)
            #pragma unroll
            for (int r = 0; r < 4; ++r) {
                int m = mw0 + i*16 + lg*4 + r;
                int n = nw0 + j*16 + lr;
                out[(size_t)m * EE + n] = acc[i][j][r] + bo[n];
            }
}

// ---------------------------------------------------------------- launch
extern "C" void kernel_launch(void* const* d_in, const int* in_sizes, int n_in,
                              void* d_out, int out_size, void* d_ws, size_t ws_size,
                              hipStream_t stream) {
    const float* values = (const float*)d_in[0];
    const float* keys   = (const float*)d_in[1];
    const float* query  = (const float*)d_in[2];
    const int*   mask   = (const int*)d_in[3];
    const float* Wv     = (const float*)d_in[4];
    const float* Wk     = (const float*)d_in[5];
    const float* Wq     = (const float*)d_in[6];
    const float* Wo     = (const float*)d_in[7];
    const float* bo     = (const float*)d_in[8];
    float* out = (float*)d_out;

    char* ws = (char*)d_ws;
    const size_t ACT = (size_t)MM * EE;   // 4194304 elems
    bf16* QP = (bf16*)ws;
    bf16* KP = QP + ACT;
    bf16* VT = KP + ACT;
    bf16* AO = VT + ACT;
    unsigned long long* MW = (unsigned long long*)(AO + ACT);   // 524288 words
    float* OP = (float*)(MW + (size_t)BB * SS * NT);            // 2 * 4.19M f32
    float* LP = OP + 2 * ACT;                                   // 2 * 65536 f32
    // total: 32MB + 4MB + 33.5MB + 0.5MB = ~70MB

    k_gemm_qkv<<<dim3(4, 64, 4), 256, 0, stream>>>(
        query, keys, values, Wq, Wk, Wv, QP, KP, VT, mask, MW);
    k_attn<<<dim3(SS/128, HH, BB*2), 256, 0, stream>>>(QP, KP, VT, MW, OP, LP);
    k_combine<<<(MM*EE/4)/256, 256, 0, stream>>>(OP, LP, AO);
    k_gemm_out<<<dim3(EE/128, MM/128, 1), 256, 0, stream>>>(AO, Wo, bo, out);
}

// Round 10
// 190.907 us; speedup vs baseline: 1.3207x; 1.1040x over previous
//
#include <hip/hip_runtime.h>
#include <hip/hip_bf16.h>
#include <stdint.h>

// Problem constants
#define BB  2
#define SS  4096
#define EE  512
#define HH  8
#define HDD 64
#define MM  (BB*SS)   // 8192
#define NT  (SS/64)   // 64 k-tiles
#define NTH (NT/2)    // 32 k-tiles per split-half

typedef __bf16 bf16;
typedef __attribute__((ext_vector_type(8))) __bf16 bf16x8;
typedef __attribute__((ext_vector_type(4))) __bf16 bf16x4;
typedef __attribute__((ext_vector_type(4))) float  f32x4;
typedef __attribute__((ext_vector_type(16))) float f32x16;

#if __has_builtin(__builtin_amdgcn_exp2f)
#define EXP2F(x) __builtin_amdgcn_exp2f(x)
#else
#define EXP2F(x) __builtin_exp2f(x)
#endif

static __device__ __forceinline__ f32x4 mfma16(bf16x8 a, bf16x8 b, f32x4 c) {
    return __builtin_amdgcn_mfma_f32_16x16x32_bf16(a, b, c, 0, 0, 0);
}
static __device__ __forceinline__ f32x16 mfma32(bf16x8 a, bf16x8 b, f32x16 c) {
    return __builtin_amdgcn_mfma_f32_32x32x16_bf16(a, b, c, 0, 0, 0);
}
static __device__ __forceinline__ bf16x8 ldg8(const bf16* p) {
    return *reinterpret_cast<const bf16x8*>(p);
}
static __device__ __forceinline__ bf16x8 cvt8(float4 a, float4 b) {
    bf16x8 o;
    o[0]=(bf16)a.x; o[1]=(bf16)a.y; o[2]=(bf16)a.z; o[3]=(bf16)a.w;
    o[4]=(bf16)b.x; o[5]=(bf16)b.y; o[6]=(bf16)b.z; o[7]=(bf16)b.w;
    return o;
}
static __device__ __forceinline__ uint32_t pk2(float a, float b) {
    union { __bf16 h[2]; uint32_t u; } x;
    x.h[0] = (__bf16)a; x.h[1] = (__bf16)b; return x.u;
}
static __device__ __forceinline__ bf16x8 frag4(uint32_t a, uint32_t b, uint32_t c, uint32_t d) {
    union { uint32_t u[4]; bf16x8 v; } x;
    x.u[0]=a; x.u[1]=b; x.u[2]=c; x.u[3]=d; return x.v;
}
// async global->LDS, 16B per lane; lds dest is wave-uniform base (HW adds lane*16)
static __device__ __forceinline__ void gload16(const bf16* g, char* lds) {
    __builtin_amdgcn_global_load_lds(
        (const __attribute__((address_space(1))) void*)g,
        (__attribute__((address_space(3))) void*)lds,
        16, 0, 0);
}

// ---------------------------------------------------------------- mask pack
// mask[b,1,q,k] int32 -> bit words tile-major: MW[(b*NT + kt)*S + q].
// Batch axis = q (w + 64j <=> q + j): 8 independent 256B load streams per
// wave AND 8 consecutive MW words per batch (coalesced output line).
// No LDS -> 8 blocks/CU residency; 2048 blocks = fully resident.
__global__ void k_pack_mask(const int* __restrict__ mask,
                            unsigned long long* __restrict__ out) {
    const int nbases = BB * (SS / 8) * NT;   // 65536
    const int lane = threadIdx.x & 63;
    const int wid  = blockIdx.x * (blockDim.x >> 6) + (threadIdx.x >> 6);
    const int nw   = gridDim.x * (blockDim.x >> 6);   // 8192 waves
    for (int bi = wid; bi < nbases; bi += nw) {
        const int b   = bi >> 15;
        const int rem = bi & 32767;
        const int q8  = rem >> 6;
        const int kt  = rem & 63;
        const size_t w0 = ((size_t)(b * SS + q8 * 8) * NT + kt);
        int v[8];
        #pragma unroll
        for (int j = 0; j < 8; ++j)
            v[j] = mask[(w0 + (size_t)j * 64) * 64 + lane];
        unsigned long long wd[8];
        #pragma unroll
        for (int j = 0; j < 8; ++j)
            wd[j] = __ballot(v[j] != 0);
        if (lane == 0) {
            unsigned long long* dst = out + ((size_t)b * NT + kt) * SS + q8 * 8;
            #pragma unroll
            for (int j = 0; j < 8; ++j) dst[j] = wd[j];
        }
    }
}

// ---------------------------------------------------------------- QKV GEMM
// LDS-staged, double-buffered, reg-staged fp32->bf16 convert.
// z=0: q -> QP [M,E]; z=1: k -> KP [M,E]; z=2: v -> VT [B,E,S]
__global__ __launch_bounds__(256) void k_gemm_qkv(
    const float* __restrict__ XQ, const float* __restrict__ XK, const float* __restrict__ XV,
    const float* __restrict__ WQ, const float* __restrict__ WK, const float* __restrict__ WV,
    bf16* __restrict__ QP, bf16* __restrict__ KP, bf16* __restrict__ VT)
{
    const int z = blockIdx.z;
    const float* A = (z == 0) ? XQ : (z == 1) ? XK : XV;
    const float* W = (z == 0) ? WQ : (z == 1) ? WK : WV;

    const int tid = threadIdx.x;
    const int lane = tid & 63, wave = tid >> 6;
    const int lr = lane & 15, lg = lane >> 4;
    const int m0 = blockIdx.y * 128, n0 = blockIdx.x * 128;

    __shared__ alignas(16) bf16 As[2][128 * 32];
    __shared__ alignas(16) bf16 Bs[2][128 * 32];

    // staging: thread covers half a row (16 f32 = 2 chunks of 16B bf16)
    const int srow = tid >> 1, shalf = tid & 1;
    const float* Ag = A + (size_t)(m0 + srow) * EE + shalf * 16;
    const float* Wg = W + (size_t)(n0 + srow) * EE + shalf * 16;
    const int sw0 = srow * 64 + ((((shalf * 2)    ) ^ ((srow >> 1) & 3)) << 4);
    const int sw1 = srow * 64 + ((((shalf * 2) + 1) ^ ((srow >> 1) & 3)) << 4);

    // fragment read byte offsets (chunk ^= (row>>1)&3 swizzle -> 2-way, free)
    int aoff[4], boff[4];
    {
        const int mw = (wave >> 1) * 64, nw = (wave & 1) * 64;
        #pragma unroll
        for (int i = 0; i < 4; ++i) { int r = mw + i*16 + lr; aoff[i] = r*64 + ((lg ^ ((r>>1)&3)) << 4); }
        #pragma unroll
        for (int j = 0; j < 4; ++j) { int r = nw + j*16 + lr; boff[j] = r*64 + ((lg ^ ((r>>1)&3)) << 4); }
    }

    f32x4 acc[4][4] = {};
    float4 sa0, sa1, sa2, sa3, sb0, sb1, sb2, sb3;

    sa0 = *(const float4*)(Ag);     sa1 = *(const float4*)(Ag + 4);
    sa2 = *(const float4*)(Ag + 8); sa3 = *(const float4*)(Ag + 12);
    sb0 = *(const float4*)(Wg);     sb1 = *(const float4*)(Wg + 4);
    sb2 = *(const float4*)(Wg + 8); sb3 = *(const float4*)(Wg + 12);
    {
        char* ab = (char*)As[0]; char* bb = (char*)Bs[0];
        *(bf16x8*)(ab + sw0) = cvt8(sa0, sa1);
        *(bf16x8*)(ab + sw1) = cvt8(sa2, sa3);
        *(bf16x8*)(bb + sw0) = cvt8(sb0, sb1);
        *(bf16x8*)(bb + sw1) = cvt8(sb2, sb3);
    }
    __syncthreads();

    for (int kb = 0; kb < 16; ++kb) {
        if (kb + 1 < 16) {   // T14: issue next-step loads before compute
            const float* An = Ag + (kb + 1) * 32;
            const float* Wn = Wg + (kb + 1) * 32;
            sa0 = *(const float4*)(An);     sa1 = *(const float4*)(An + 4);
            sa2 = *(const float4*)(An + 8); sa3 = *(const float4*)(An + 12);
            sb0 = *(const float4*)(Wn);     sb1 = *(const float4*)(Wn + 4);
            sb2 = *(const float4*)(Wn + 8); sb3 = *(const float4*)(Wn + 12);
        }
        const char* ab = (const char*)As[kb & 1];
        const char* bb = (const char*)Bs[kb & 1];
        bf16x8 af[4], bw[4];
        #pragma unroll
        for (int i = 0; i < 4; ++i) af[i] = *(const bf16x8*)(ab + aoff[i]);
        #pragma unroll
        for (int j = 0; j < 4; ++j) bw[j] = *(const bf16x8*)(bb + boff[j]);
        #pragma unroll
        for (int i = 0; i < 4; ++i)
            #pragma unroll
            for (int j = 0; j < 4; ++j)
                acc[i][j] = mfma16(af[i], bw[j], acc[i][j]);
        __syncthreads();
        if (kb + 1 < 16) {
            char* ab2 = (char*)As[(kb + 1) & 1]; char* bb2 = (char*)Bs[(kb + 1) & 1];
            *(bf16x8*)(ab2 + sw0) = cvt8(sa0, sa1);
            *(bf16x8*)(ab2 + sw1) = cvt8(sa2, sa3);
            *(bf16x8*)(bb2 + sw0) = cvt8(sb0, sb1);
            *(bf16x8*)(bb2 + sw1) = cvt8(sb2, sb3);
        }
        __syncthreads();
    }

    const int mw0 = m0 + (wave >> 1) * 64, nw0 = n0 + (wave & 1) * 64;
    if (z < 2) {
        bf16* O = (z == 0) ? QP : KP;
        #pragma unroll
        for (int i = 0; i < 4; ++i)
            #pragma unroll
            for (int j = 0; j < 4; ++j)
                #pragma unroll
                for (int r = 0; r < 4; ++r) {
                    int m = mw0 + i*16 + lg*4 + r;
                    int n = nw0 + j*16 + lr;
                    O[(size_t)m * EE + n] = (bf16)acc[i][j][r];
                }
    } else {
        #pragma unroll
        for (int i = 0; i < 4; ++i) {
            int mrow = mw0 + i*16 + lg*4;
            int bidx = mrow >> 12;
            int s0   = mrow & (SS - 1);
            #pragma unroll
            for (int j = 0; j < 4; ++j) {
                int n = nw0 + j*16 + lr;
                bf16x4 v = { (bf16)acc[i][j][0], (bf16)acc[i][j][1],
                             (bf16)acc[i][j][2], (bf16)acc[i][j][3] };
                *reinterpret_cast<bf16x4*>(VT + ((size_t)bidx * EE + n) * SS + s0) = v;
            }
        }
    }
}

// ---------------------------------------------------------------- attention
// Swapped-QK 32x32 MFMA flash attention, no-max softmax, KV-split x2.
// global_load_lds staging (swizzle-via-source), two-pass k-halves.
// No setprio fences (round-9 win: scheduler interleaves the two passes).
// grid (S/128, H, B*2), block 256 (4 waves); wave owns 32 q-rows.
__global__ __launch_bounds__(256, 3) void k_attn(
    const bf16* __restrict__ QP, const bf16* __restrict__ KP,
    const bf16* __restrict__ VT, const unsigned long long* __restrict__ MW,
    float* __restrict__ OP, float* __restrict__ LP)
{
    const int zz = blockIdx.z;
    const int b = zz >> 1, half = zz & 1;
    const int h = blockIdx.y;
    const int tid  = threadIdx.x;
    const int lane = tid & 63;
    const int wave = tid >> 6;
    const int lq = lane & 31;
    const int hi = lane >> 5;
    const int q0 = blockIdx.x * 128 + wave * 32;
    const int kt0 = half * NTH;
    constexpr float SC = 0.044194173824159216f * 1.4426950408889634f; // 1/sqrt(512)*log2(e)

    // per buffer: K tile 8KB @ [0,8192), V tile 8KB @ [8192,16384)
    __shared__ alignas(16) char smem[2][16384];

    // ---- Q fragments (B-operand), prescaled by SC once.
    const bf16* Qb = QP + (size_t)(b * SS + q0 + lq) * EE + h * HDD + hi * 8;
    bf16x8 qf[4];
    #pragma unroll
    for (int dc = 0; dc < 4; ++dc) {
        bf16x8 t = ldg8(Qb + dc * 16);
        bf16x8 o;
        #pragma unroll
        for (int j = 0; j < 8; ++j) o[j] = (bf16)((float)t[j] * SC);
        qf[dc] = o;
    }

    // ---- global_load_lds staging geometry
    const int srow = wave * 16 + (lane >> 3);
    const int sch  = (lane & 7) ^ (srow & 7);
    const bf16* Kg = KP + ((size_t)(b * SS) + kt0 * 64 + srow) * EE + h * HDD + (sch << 3);
    const bf16* Vg = VT + ((size_t)(b * EE) + h * HDD + srow) * SS + kt0 * 64 + (sch << 3);

    // ---- static per-lane fragment read offsets (chunk ^= row&7 swizzle)
    int koff[2][4];
    #pragma unroll
    for (int hf = 0; hf < 2; ++hf) {
        const int rk = lq + 32 * hf;
        #pragma unroll
        for (int dc = 0; dc < 4; ++dc)
            koff[hf][dc] = rk * 128 + (((dc * 2 + hi) ^ (rk & 7)) << 4);
    }

    const unsigned long long* Mb = MW + (size_t)b * NT * SS + (size_t)kt0 * SS + (q0 + lq);

    f32x16 o0 = {}, o1 = {};   // O[q=crow(r,hi)][d = dblk*32 + lq]
    float lsum = 0.f;

#define STAGE(buf, t) do {                                        \
        const bf16* kg_ = Kg + (size_t)(t) * 64 * EE;             \
        const bf16* vg_ = Vg + (t) * 64;                          \
        char* kb_ = smem[buf] + wave * 2048;                      \
        char* vb_ = smem[buf] + 8192 + wave * 2048;               \
        gload16(kg_,          kb_);                               \
        gload16(kg_ + 8 * EE, kb_ + 1024);                        \
        gload16(vg_,          vb_);                               \
        gload16(vg_ + 8 * SS, vb_ + 1024);                        \
    } while (0)

    // ---- prologue: stage tile 0
    STAGE(0, 0);
    asm volatile("s_waitcnt vmcnt(0)" ::: "memory");
    __syncthreads();

    for (int kt = 0; kt < NTH; ++kt) {
        const int cur = kt & 1;

        // issue next-tile async loads into the buffer freed at last barrier
        if (kt + 1 < NTH) STAGE(cur ^ 1, kt + 1);
        __builtin_amdgcn_sched_barrier(0);

        const char* rb = smem[cur];
        const unsigned long long w = Mb[(size_t)kt * SS];

        // ================= PASS A: k-rows 0..31 of the tile =================
        {
            bf16x8 kf[4];
            #pragma unroll
            for (int dc = 0; dc < 4; ++dc)
                kf[dc] = *reinterpret_cast<const bf16x8*>(rb + koff[0][dc]);
            f32x16 s = {};
            #pragma unroll
            for (int dc = 0; dc < 4; ++dc) s = mfma32(kf[dc], qf[dc], s);

            const uint32_t hw = (uint32_t)(w >> (4 * hi));
            uint32_t wA[8];
            #pragma unroll
            for (int i = 0; i < 8; ++i) {
                const int r0 = 2*i, r1 = 2*i+1;
                const int pos0 = (r0 & 3) + 8 * (r0 >> 2);
                const int pos1 = (r1 & 3) + 8 * (r1 >> 2);
                float e0 = EXP2F(s[r0]);
                float e1 = EXP2F(s[r1]);
                e0 = (hw & (1u << pos0)) ? e0 : 0.f;
                e1 = (hw & (1u << pos1)) ? e1 : 0.f;
                lsum += e0 + e1;
                wA[i] = pk2(e0, e1);
            }
            uint32_t ra0 = __shfl_xor((int)(hi ? wA[0] : wA[2]), 32);
            uint32_t ra1 = __shfl_xor((int)(hi ? wA[1] : wA[3]), 32);
            uint32_t ra2 = __shfl_xor((int)(hi ? wA[4] : wA[6]), 32);
            uint32_t ra3 = __shfl_xor((int)(hi ? wA[5] : wA[7]), 32);
            bf16x8 pa0 = frag4(hi ? ra0 : wA[0], hi ? ra1 : wA[1],
                               hi ? wA[2] : ra0, hi ? wA[3] : ra1);
            bf16x8 pa1 = frag4(hi ? ra2 : wA[4], hi ? ra3 : wA[5],
                               hi ? wA[6] : ra2, hi ? wA[7] : ra3);

            bf16x8 v00 = *reinterpret_cast<const bf16x8*>(rb + 8192 + koff[0][0]);
            bf16x8 v01 = *reinterpret_cast<const bf16x8*>(rb + 8192 + koff[0][1]);
            bf16x8 v10 = *reinterpret_cast<const bf16x8*>(rb + 8192 + koff[1][0]);
            bf16x8 v11 = *reinterpret_cast<const bf16x8*>(rb + 8192 + koff[1][1]);
            o0 = mfma32(pa0, v00, o0);
            o0 = mfma32(pa1, v01, o0);
            o1 = mfma32(pa0, v10, o1);
            o1 = mfma32(pa1, v11, o1);
        }

        // ================= PASS B: k-rows 32..63 of the tile ================
        {
            bf16x8 kf[4];
            #pragma unroll
            for (int dc = 0; dc < 4; ++dc)
                kf[dc] = *reinterpret_cast<const bf16x8*>(rb + koff[1][dc]);
            f32x16 s = {};
            #pragma unroll
            for (int dc = 0; dc < 4; ++dc) s = mfma32(kf[dc], qf[dc], s);

            const uint32_t hw = (uint32_t)(w >> (32 + 4 * hi));
            uint32_t wB[8];
            #pragma unroll
            for (int i = 0; i < 8; ++i) {
                const int r0 = 2*i, r1 = 2*i+1;
                const int pos0 = (r0 & 3) + 8 * (r0 >> 2);
                const int pos1 = (r1 & 3) + 8 * (r1 >> 2);
                float e0 = EXP2F(s[r0]);
                float e1 = EXP2F(s[r1]);
                e0 = (hw & (1u << pos0)) ? e0 : 0.f;
                e1 = (hw & (1u << pos1)) ? e1 : 0.f;
                lsum += e0 + e1;
                wB[i] = pk2(e0, e1);
            }
            uint32_t rb0 = __shfl_xor((int)(hi ? wB[0] : wB[2]), 32);
            uint32_t rb1 = __shfl_xor((int)(hi ? wB[1] : wB[3]), 32);
            uint32_t rb2 = __shfl_xor((int)(hi ? wB[4] : wB[6]), 32);
            uint32_t rb3 = __shfl_xor((int)(hi ? wB[5] : wB[7]), 32);
            bf16x8 pb0 = frag4(hi ? rb0 : wB[0], hi ? rb1 : wB[1],
                               hi ? wB[2] : rb0, hi ? wB[3] : rb1);
            bf16x8 pb1 = frag4(hi ? rb2 : wB[4], hi ? rb3 : wB[5],
                               hi ? wB[6] : rb2, hi ? wB[7] : rb3);

            bf16x8 v00 = *reinterpret_cast<const bf16x8*>(rb + 8192 + koff[0][2]);
            bf16x8 v01 = *reinterpret_cast<const bf16x8*>(rb + 8192 + koff[0][3]);
            bf16x8 v10 = *reinterpret_cast<const bf16x8*>(rb + 8192 + koff[1][2]);
            bf16x8 v11 = *reinterpret_cast<const bf16x8*>(rb + 8192 + koff[1][3]);
            o0 = mfma32(pb0, v00, o0);
            o0 = mfma32(pb1, v01, o0);
            o1 = mfma32(pb0, v10, o1);
            o1 = mfma32(pb1, v11, o1);
        }

        // ---- next-tile loads have landed (issued a full tile ago); release buf
        asm volatile("s_waitcnt vmcnt(0)" ::: "memory");
        __syncthreads();
    }
#undef STAGE

    // ---- partial row-sum: this lane + partner cover this half's k range
    float ltot = lsum + __shfl_xor(lsum, 32);

    // ---- store raw partials; combine kernel normalizes
    float* OPb = OP + ((((size_t)half * BB + b) * HH + h) * SS + q0) * 64;
    float* LPb = LP + (((size_t)half * BB + b) * HH + h) * SS + q0;
    #pragma unroll
    for (int r = 0; r < 16; ++r) {
        int qr = (r & 3) + 8 * (r >> 2) + 4 * hi;
        OPb[(size_t)qr * 64 + lq]      = o0[r];
        OPb[(size_t)qr * 64 + 32 + lq] = o1[r];
    }
    if (hi == 0) LPb[lq] = ltot;   // lane lq holds q-row lq's partial sum
}

// ---------------------------------------------------------------- combine
// AO[b,q,h*64+d] = (OP0 + OP1) / (LP0 + LP1), bf16
__global__ __launch_bounds__(256) void k_combine(
    const float* __restrict__ OP, const float* __restrict__ LP,
    bf16* __restrict__ AO)
{
    const int t = blockIdx.x * 256 + threadIdx.x;      // 2^20 threads
    const int dg = t & 15;
    const int q  = (t >> 4) & (SS - 1);
    const int hb = t >> 16;
    const int h  = hb & 7;
    const int b  = hb >> 3;
    const size_t HALFO = (size_t)BB * HH * SS * 64;
    const size_t HALFL = (size_t)BB * HH * SS;
    const size_t poff = ((((size_t)b * HH + h) * SS) + q) * 64 + dg * 4;
    const size_t loff = (((size_t)b * HH + h) * SS) + q;
    float4 oa = *(const float4*)(OP + poff);
    float4 ob = *(const float4*)(OP + HALFO + poff);
    float inv = 1.0f / (LP[loff] + LP[HALFL + loff]);
    bf16x4 o = { (bf16)((oa.x + ob.x) * inv), (bf16)((oa.y + ob.y) * inv),
                 (bf16)((oa.z + ob.z) * inv), (bf16)((oa.w + ob.w) * inv) };
    *reinterpret_cast<bf16x4*>(AO + ((size_t)(b * SS + q)) * EE + h * 64 + dg * 4) = o;
}

// ---------------------------------------------------------------- out proj
// LDS-staged; A is bf16 (AO), W fp32, out fp32 + bias.
__global__ __launch_bounds__(256) void k_gemm_out(
    const bf16* __restrict__ AO, const float* __restrict__ WO,
    const float* __restrict__ bo, float* __restrict__ out)
{
    const int tid = threadIdx.x;
    const int lane = tid & 63, wave = tid >> 6;
    const int lr = lane & 15, lg = lane >> 4;
    const int m0 = blockIdx.y * 128, n0 = blockIdx.x * 128;

    __shared__ alignas(16) bf16 As[2][128 * 32];
    __shared__ alignas(16) bf16 Bs[2][128 * 32];

    const int srow = tid >> 1, shalf = tid & 1;
    const bf16*  Ag = AO + (size_t)(m0 + srow) * EE + shalf * 16;
    const float* Wg = WO + (size_t)(n0 + srow) * EE + shalf * 16;
    const int sw0 = srow * 64 + ((((shalf * 2)    ) ^ ((srow >> 1) & 3)) << 4);
    const int sw1 = srow * 64 + ((((shalf * 2) + 1) ^ ((srow >> 1) & 3)) << 4);

    int aoff[4], boff[4];
    {
        const int mw = (wave >> 1) * 64, nw = (wave & 1) * 64;
        #pragma unroll
        for (int i = 0; i < 4; ++i) { int r = mw + i*16 + lr; aoff[i] = r*64 + ((lg ^ ((r>>1)&3)) << 4); }
        #pragma unroll
        for (int j = 0; j < 4; ++j) { int r = nw + j*16 + lr; boff[j] = r*64 + ((lg ^ ((r>>1)&3)) << 4); }
    }

    f32x4 acc[4][4] = {};
    bf16x8 qa0, qa1;
    float4 sb0, sb1, sb2, sb3;

    qa0 = ldg8(Ag); qa1 = ldg8(Ag + 8);
    sb0 = *(const float4*)(Wg);     sb1 = *(const float4*)(Wg + 4);
    sb2 = *(const float4*)(Wg + 8); sb3 = *(const float4*)(Wg + 12);
    {
        char* ab = (char*)As[0]; char* bb = (char*)Bs[0];
        *(bf16x8*)(ab + sw0) = qa0;
        *(bf16x8*)(ab + sw1) = qa1;
        *(bf16x8*)(bb + sw0) = cvt8(sb0, sb1);
        *(bf16x8*)(bb + sw1) = cvt8(sb2, sb3);
    }
    __syncthreads();

    for (int kb = 0; kb < 16; ++kb) {
        if (kb + 1 < 16) {
            const bf16*  An = Ag + (kb + 1) * 32;
            const float* Wn = Wg + (kb + 1) * 32;
            qa0 = ldg8(An); qa1 = ldg8(An + 8);
            sb0 = *(const float4*)(Wn);     sb1 = *(const float4*)(Wn + 4);
            sb2 = *(const float4*)(Wn + 8); sb3 = *(const float4*)(Wn + 12);
        }
        const char* ab = (const char*)As[kb & 1];
        const char* bb = (const char*)Bs[kb & 1];
        bf16x8 af[4], bw[4];
        #pragma unroll
        for (int i = 0; i < 4; ++i) af[i] = *(const bf16x8*)(ab + aoff[i]);
        #pragma unroll
        for (int j = 0; j < 4; ++j) bw[j] = *(const bf16x8*)(bb + boff[j]);
        #pragma unroll
        for (int i = 0; i < 4; ++i)
            #pragma unroll
            for (int j = 0; j < 4; ++j)
                acc[i][j] = mfma16(af[i], bw[j], acc[i][j]);
        __syncthreads();
        if (kb + 1 < 16) {
            char* ab2 = (char*)As[(kb + 1) & 1]; char* bb2 = (char*)Bs[(kb + 1) & 1];
            *(bf16x8*)(ab2 + sw0) = qa0;
            *(bf16x8*)(ab2 + sw1) = qa1;
            *(bf16x8*)(bb2 + sw0) = cvt8(sb0, sb1);
            *(bf16x8*)(bb2 + sw1) = cvt8(sb2, sb3);
        }
        __syncthreads();
    }

    const int mw0 = m0 + (wave >> 1) * 64, nw0 = n0 + (wave & 1) * 64;
    #pragma unroll
    for (int i = 0; i < 4; ++i)
        #pragma unroll
        for (int j = 0; j < 4; ++j)
            #pragma unroll
            for (int r = 0; r < 4; ++r) {
                int m = mw0 + i*16 + lg*4 + r;
                int n = nw0 + j*16 + lr;
                out[(size_t)m * EE + n] = acc[i][j][r] + bo[n];
            }
}

// ---------------------------------------------------------------- launch
extern "C" void kernel_launch(void* const* d_in, const int* in_sizes, int n_in,
                              void* d_out, int out_size, void* d_ws, size_t ws_size,
                              hipStream_t stream) {
    const float* values = (const float*)d_in[0];
    const float* keys   = (const float*)d_in[1];
    const float* query  = (const float*)d_in[2];
    const int*   mask   = (const int*)d_in[3];
    const float* Wv     = (const float*)d_in[4];
    const float* Wk     = (const float*)d_in[5];
    const float* Wq     = (const float*)d_in[6];
    const float* Wo     = (const float*)d_in[7];
    const float* bo     = (const float*)d_in[8];
    float* out = (float*)d_out;

    char* ws = (char*)d_ws;
    const size_t ACT = (size_t)MM * EE;   // 4194304 elems
    bf16* QP = (bf16*)ws;
    bf16* KP = QP + ACT;
    bf16* VT = KP + ACT;
    bf16* AO = VT + ACT;
    unsigned long long* MW = (unsigned long long*)(AO + ACT);   // 524288 words
    float* OP = (float*)(MW + (size_t)BB * SS * NT);            // 2 * 4.19M f32
    float* LP = OP + 2 * ACT;                                   // 2 * 65536 f32
    // total: 32MB + 4MB + 33.5MB + 0.5MB = ~70MB

    k_pack_mask<<<2048, 256, 0, stream>>>(mask, MW);
    k_gemm_qkv<<<dim3(EE/128, MM/128, 3), 256, 0, stream>>>(
        query, keys, values, Wq, Wk, Wv, QP, KP, VT);
    k_attn<<<dim3(SS/128, HH, BB*2), 256, 0, stream>>>(QP, KP, VT, MW, OP, LP);
    k_combine<<<(MM*EE/4)/256, 256, 0, stream>>>(OP, LP, AO);
    k_gemm_out<<<dim3(EE/128, MM/128, 1), 256, 0, stream>>>(AO, Wo, bo, out);
}